// Round 16
// baseline (81.553 us; speedup 1.0000x reference)
//
#include <hip/hip_runtime.h>
#include <hip/hip_fp16.h>

#define T    65536
#define TOUT 65532
#define NB   16
#define CH   32
#define NF   32
#define KS   5
#define BM   128
#define NSUB 4             // subtiles per conv block (512 rows)
#define NCHB 2048          // chsum grid; 2048*4096 float4 == NB*T*CH/4 exactly

typedef _Float16 f16x8 __attribute__((ext_vector_type(8)));
typedef _Float16 f16x4 __attribute__((ext_vector_type(4)));
typedef float    f32x4 __attribute__((ext_vector_type(4)));

// ws layout: ws[32] = scalar s (fallback only); partials[2048][32] at byte 256.
// Cross-block communication ONLY via kernel boundaries — NO device-scope
// ordered atomics (gfx950: release/acquire => L2 writeback/invalidate storm,
// measured R6/R11). s is computed redundantly per conv block (prologue).

__device__ __forceinline__ f16x4 cvt4(float4 v) {
    f16x4 h;
    h[0] = (_Float16)v.x; h[1] = (_Float16)v.y;
    h[2] = (_Float16)v.z; h[3] = (_Float16)v.w;
    return h;
}

// ---- K1: contiguous streaming chsum, plain cached loads (park x in L3) ----
__global__ __launch_bounds__(256) void chsum7_kernel(const float* __restrict__ x,
                                                     float* __restrict__ partials) {
    __shared__ float tot[CH];
    const int tid  = threadIdx.x;
    const int lane = tid & 63;
    if (tid < CH) tot[tid] = 0.f;
    __syncthreads();

    const float4* x4 = (const float4*)x;
    const size_t base = (size_t)blockIdx.x * 4096;   // contiguous 64 KB per block
    float s0 = 0.f, s1 = 0.f, s2 = 0.f, s3 = 0.f;
#pragma unroll 8
    for (int q = 0; q < 16; ++q) {
        float4 v = x4[base + (size_t)q * 256 + tid];  // cached: fills L3 for conv
        s0 += v.x; s1 += v.y; s2 += v.z; s3 += v.w;
    }
#pragma unroll
    for (int m = 8; m <= 32; m <<= 1) {    // lanes {l,l^8,l^16,l^32} share channel group
        s0 += __shfl_xor(s0, m, 64);
        s1 += __shfl_xor(s1, m, 64);
        s2 += __shfl_xor(s2, m, 64);
        s3 += __shfl_xor(s3, m, 64);
    }
    if (lane < 8) {
        const int cc = lane * 4;
        atomicAdd(&tot[cc + 0], s0);       // LDS atomics only
        atomicAdd(&tot[cc + 1], s1);
        atomicAdd(&tot[cc + 2], s2);
        atomicAdd(&tot[cc + 3], s3);
    }
    __syncthreads();
    if (tid < CH) partials[(size_t)blockIdx.x * CH + tid] = tot[tid];  // plain store
}

// ---- K2: conv from f32 x (L3-hot); per-block redundant s prologue (no atomics) ----
__global__ __launch_bounds__(256) void conv6_kernel(const float* __restrict__ x,
                                                    const float* __restrict__ Wconv,
                                                    const float* __restrict__ bconv,
                                                    const float* __restrict__ Wdef,
                                                    const float* __restrict__ partials,
                                                    float* __restrict__ out) {
    __shared__ _Float16 A[(BM + 4) * 40];
    __shared__ _Float16 Wt[KS * CH * 40];
    __shared__ float ltot[CH];
    __shared__ float hb[4][CH], tb[4][CH];
    __shared__ float red[256];
    __shared__ float s_sh;

    const int tid  = threadIdx.x;
    const int b    = blockIdx.y;
    const int t0   = blockIdx.x * (NSUB * BM);
    const int c0   = (tid & 7) * 4;
    const int srow = tid >> 3;               // 0..31

    const float* xb = x + (size_t)b * T * CH;

    // A-staging register buffers: rows srow+{0,32,64,96,128(if tid<32)}, f32
    float4 ra0, ra1, ra2, ra3, ra4;
    auto LOADA = [&](int sub) {
        const float* p = xb + (size_t)(t0 + sub * BM + srow) * CH + c0;
        ra0 = *(const float4*)(p);
        ra1 = *(const float4*)(p + 32 * CH);
        ra2 = *(const float4*)(p + 64 * CH);
        ra3 = *(const float4*)(p + 96 * CH);
        if (tid < 32) {
            int t = t0 + sub * BM + 128 + srow;
            ra4 = (t < T) ? *(const float4*)(xb + (size_t)t * CH + c0)
                          : make_float4(0.f, 0.f, 0.f, 0.f);
        }
    };
    auto WRITEA = [&]() {
        *(f16x4*)&A[(srow      ) * 40 + c0] = cvt4(ra0);
        *(f16x4*)&A[(srow + 32 ) * 40 + c0] = cvt4(ra1);
        *(f16x4*)&A[(srow + 64 ) * 40 + c0] = cvt4(ra2);
        *(f16x4*)&A[(srow + 96 ) * 40 + c0] = cvt4(ra3);
        if (tid < 32)
            *(f16x4*)&A[(128 + srow) * 40 + c0] = cvt4(ra4);
    };

    LOADA(0);                                // sub-0 loads fly under the s-prologue

    // ---- prologue: redundant s computation (partials L2/L3-hot, no atomics) ----
    if (tid < CH) ltot[tid] = 0.f;
    __syncthreads();
    {
        const float4* p4 = (const float4*)partials;   // 16384 float4, coalesced
        float s0 = 0.f, s1 = 0.f, s2 = 0.f, s3 = 0.f;
#pragma unroll 8
        for (int i = 0; i < 64; ++i) {
            float4 v = p4[i * 256 + tid];
            s0 += v.x; s1 += v.y; s2 += v.z; s3 += v.w;
        }
        int cc = (tid & 7) * 4;
        atomicAdd(&ltot[cc + 0], s0);        // LDS atomics only
        atomicAdd(&ltot[cc + 1], s1);
        atomicAdd(&ltot[cc + 2], s2);
        atomicAdd(&ltot[cc + 3], s3);
    }
    {
        int j = tid >> 5, c = tid & 31;      // j in 0..7
        int row = (j < 4) ? j : (T - 8 + j);
        float e = 0.f;
        for (int bb = 0; bb < NB; ++bb)
            e += x[((size_t)bb * T + row) * CH + c];   // L3-hot edge rows
        if (j < 4) hb[j][c] = e; else tb[j - 4][c] = e;
    }
    __syncthreads();
    {
        float term = 0.f;
        if (tid < KS * CH) {
            int k = tid >> 5, c = tid & 31;
            float wf = 0.f;
            const float* wp = &Wconv[(size_t)tid * NF];
            for (int f = 0; f < NF; ++f) wf += wp[f];
            float S = ltot[c];
            for (int jj = 0; jj < k; ++jj) S -= hb[jj][c];
            for (int jj = k; jj < 4; ++jj) S -= tb[jj][c];
            term = wf * S;
        }
        red[tid] = term;
        __syncthreads();
        for (int off = 128; off > 0; off >>= 1) {
            if (tid < off) red[tid] += red[tid + off];
            __syncthreads();
        }
        if (tid == 0) {
            float sum_b = 0.f;
            for (int f = 0; f < NF; ++f) sum_b += bconv[f];
            float mean_off = red[0] / (float)((size_t)NB * TOUT * NF) + sum_b / (float)NF;
            float s = 0.f;
            for (int k = 0; k < KS; ++k) {
                float pn = mean_off + (float)(k - 2);
                s += Wdef[k] * fmaxf(0.f, 1.f - fabsf(pn));
            }
            s_sh = s;
        }
    }

    // ---- Wt staging + sub-0 LDS write ----
    {
        const float4* w4 = (const float4*)Wconv;
#pragma unroll
        for (int j = 0; j < 5; ++j) {
            int i4 = tid + j * 256;
            float4 v = w4[i4];
            int fi = i4 * 4;
            int k = fi >> 10, c = (fi >> 5) & 31, f = fi & 31;
            _Float16* wrow = &Wt[(k * CH + f) * 40 + c];
            wrow[0 * 40] = (_Float16)v.x;
            wrow[1 * 40] = (_Float16)v.y;
            wrow[2 * 40] = (_Float16)v.z;
            wrow[3 * 40] = (_Float16)v.w;
        }
    }
    WRITEA();
    __syncthreads();

    const int lane = tid & 63;
    const int wave = tid >> 6;
    const int rowbase = wave * 32;
    const int lrow = lane & 15;
    const int kgrp = lane >> 4;
    const int col0 = lane & 15;
    const float sv  = s_sh;
    const float bc0 = bconv[col0], bc1 = bconv[col0 + 16];

#pragma unroll
    for (int sub = 0; sub < NSUB; ++sub) {
        if (sub < NSUB - 1) LOADA(sub + 1);   // next tile's loads fly under MFMA+stores

        f32x4 acc00 = {}, acc01 = {}, acc10 = {}, acc11 = {};
#pragma unroll
        for (int kk = 0; kk < KS; ++kk) {
            f16x8 a0 = *(const f16x8*)&A[(rowbase + lrow + kk) * 40 + kgrp * 8];
            f16x8 a1 = *(const f16x8*)&A[(rowbase + 16 + lrow + kk) * 40 + kgrp * 8];
            f16x8 b0 = *(const f16x8*)&Wt[(kk * CH + lrow) * 40 + kgrp * 8];
            f16x8 b1 = *(const f16x8*)&Wt[(kk * CH + 16 + lrow) * 40 + kgrp * 8];
            acc00 = __builtin_amdgcn_mfma_f32_16x16x32_f16(a0, b0, acc00, 0, 0, 0);
            acc01 = __builtin_amdgcn_mfma_f32_16x16x32_f16(a0, b1, acc01, 0, 0, 0);
            acc10 = __builtin_amdgcn_mfma_f32_16x16x32_f16(a1, b0, acc10, 0, 0, 0);
            acc11 = __builtin_amdgcn_mfma_f32_16x16x32_f16(a1, b1, acc11, 0, 0, 0);
        }

        int tsub  = t0 + sub * BM;
        int rbase = rowbase + ((lane >> 4) << 2);
#pragma unroll
        for (int reg = 0; reg < 4; ++reg) {
            int t = tsub + rbase + reg;
            if (t < TOUT) {
                float* o = &out[((size_t)b * TOUT + t) * NF];
                o[col0]      = sv * acc00[reg] + bc0;
                o[col0 + 16] = sv * acc01[reg] + bc1;
            }
            int t1 = t + 16;
            if (t1 < TOUT) {
                float* o = &out[((size_t)b * TOUT + t1) * NF];
                o[col0]      = sv * acc10[reg] + bc0;
                o[col0 + 16] = sv * acc11[reg] + bc1;
            }
        }
        if (sub < NSUB - 1) {
            __syncthreads();               // all MFMA reads of A done
            WRITEA();                      // next tile into LDS
            __syncthreads();
        }
    }
}

// ================= Fallback (R15 champion path) if ws too small =================
__global__ __launch_bounds__(256) void scalar2_kernel(const float* __restrict__ x,
                                                      const float* __restrict__ Wconv,
                                                      const float* __restrict__ bconv,
                                                      const float* __restrict__ Wdef,
                                                      const float* __restrict__ partials,
                                                      float* __restrict__ ws) {
    __shared__ float ltot[CH];
    __shared__ float hb[4][CH], tb[4][CH];
    __shared__ float partial[256];
    const int tid = threadIdx.x;
    if (tid < CH) ltot[tid] = 0.f;
    __syncthreads();
    {
        const float4* p4 = (const float4*)partials;
        float s0 = 0.f, s1 = 0.f, s2 = 0.f, s3 = 0.f;
#pragma unroll 8
        for (int i = 0; i < 64; ++i) {
            float4 v = p4[i * 256 + tid];
            s0 += v.x; s1 += v.y; s2 += v.z; s3 += v.w;
        }
        int cc = (tid & 7) * 4;
        atomicAdd(&ltot[cc + 0], s0);
        atomicAdd(&ltot[cc + 1], s1);
        atomicAdd(&ltot[cc + 2], s2);
        atomicAdd(&ltot[cc + 3], s3);
    }
    {
        int j = tid >> 5, c = tid & 31;
        int row = (j < 4) ? j : (T - 8 + j);
        float e = 0.f;
        for (int bb = 0; bb < NB; ++bb)
            e += x[((size_t)bb * T + row) * CH + c];
        if (j < 4) hb[j][c] = e; else tb[j - 4][c] = e;
    }
    __syncthreads();
    float term = 0.f;
    if (tid < KS * CH) {
        int k = tid >> 5, c = tid & 31;
        float wf = 0.f;
        const float* wp = &Wconv[(size_t)tid * NF];
        for (int f = 0; f < NF; ++f) wf += wp[f];
        float S = ltot[c];
        for (int jj = 0; jj < k; ++jj) S -= hb[jj][c];
        for (int jj = k; jj < 4; ++jj) S -= tb[jj][c];
        term = wf * S;
    }
    partial[tid] = term;
    __syncthreads();
    for (int off = 128; off > 0; off >>= 1) {
        if (tid < off) partial[tid] += partial[tid + off];
        __syncthreads();
    }
    if (tid == 0) {
        float sum_b = 0.f;
        for (int f = 0; f < NF; ++f) sum_b += bconv[f];
        float mean_off = partial[0] / (float)((size_t)NB * TOUT * NF) + sum_b / (float)NF;
        float s = 0.f;
        for (int k = 0; k < KS; ++k) {
            float pn = mean_off + (float)(k - 2);
            s += Wdef[k] * fmaxf(0.f, 1.f - fabsf(pn));
        }
        ws[CH] = s;
    }
}

__global__ __launch_bounds__(256) void conv5_kernel(const float* __restrict__ x,
                                                    const float* __restrict__ Wconv,
                                                    const float* __restrict__ bconv,
                                                    const float* __restrict__ ws,
                                                    float* __restrict__ out) {
    __shared__ _Float16 A[(BM + 4) * 40];
    __shared__ _Float16 Wt[KS * CH * 40];
    const int tid  = threadIdx.x;
    const int b    = blockIdx.y;
    const int t0   = blockIdx.x * (NSUB * BM);
    const int c0   = (tid & 7) * 4;
    const int srow = tid >> 3;
    const float* xb = x + (size_t)b * T * CH;
    float4 ra0, ra1, ra2, ra3, ra4;
    auto LOADA = [&](int sub) {
        const float* p = xb + (size_t)(t0 + sub * BM + srow) * CH + c0;
        ra0 = *(const float4*)(p);
        ra1 = *(const float4*)(p + 32 * CH);
        ra2 = *(const float4*)(p + 64 * CH);
        ra3 = *(const float4*)(p + 96 * CH);
        if (tid < 32) {
            int t = t0 + sub * BM + 128 + srow;
            ra4 = (t < T) ? *(const float4*)(xb + (size_t)t * CH + c0)
                          : make_float4(0.f, 0.f, 0.f, 0.f);
        }
    };
    auto WRITEA = [&]() {
        *(f16x4*)&A[(srow      ) * 40 + c0] = cvt4(ra0);
        *(f16x4*)&A[(srow + 32 ) * 40 + c0] = cvt4(ra1);
        *(f16x4*)&A[(srow + 64 ) * 40 + c0] = cvt4(ra2);
        *(f16x4*)&A[(srow + 96 ) * 40 + c0] = cvt4(ra3);
        if (tid < 32)
            *(f16x4*)&A[(128 + srow) * 40 + c0] = cvt4(ra4);
    };
    LOADA(0);
    {
        const float4* w4 = (const float4*)Wconv;
#pragma unroll
        for (int j = 0; j < 5; ++j) {
            int i4 = tid + j * 256;
            float4 v = w4[i4];
            int fi = i4 * 4;
            int k = fi >> 10, c = (fi >> 5) & 31, f = fi & 31;
            _Float16* wrow = &Wt[(k * CH + f) * 40 + c];
            wrow[0 * 40] = (_Float16)v.x;
            wrow[1 * 40] = (_Float16)v.y;
            wrow[2 * 40] = (_Float16)v.z;
            wrow[3 * 40] = (_Float16)v.w;
        }
    }
    WRITEA();
    __syncthreads();
    const int lane = tid & 63;
    const int wave = tid >> 6;
    const int rowbase = wave * 32;
    const int lrow = lane & 15;
    const int kgrp = lane >> 4;
    const int col0 = lane & 15;
    const float sv  = ws[CH];
    const float bc0 = bconv[col0], bc1 = bconv[col0 + 16];
#pragma unroll
    for (int sub = 0; sub < NSUB; ++sub) {
        if (sub < NSUB - 1) LOADA(sub + 1);
        f32x4 acc00 = {}, acc01 = {}, acc10 = {}, acc11 = {};
#pragma unroll
        for (int kk = 0; kk < KS; ++kk) {
            f16x8 a0 = *(const f16x8*)&A[(rowbase + lrow + kk) * 40 + kgrp * 8];
            f16x8 a1 = *(const f16x8*)&A[(rowbase + 16 + lrow + kk) * 40 + kgrp * 8];
            f16x8 b0 = *(const f16x8*)&Wt[(kk * CH + lrow) * 40 + kgrp * 8];
            f16x8 b1 = *(const f16x8*)&Wt[(kk * CH + 16 + lrow) * 40 + kgrp * 8];
            acc00 = __builtin_amdgcn_mfma_f32_16x16x32_f16(a0, b0, acc00, 0, 0, 0);
            acc01 = __builtin_amdgcn_mfma_f32_16x16x32_f16(a0, b1, acc01, 0, 0, 0);
            acc10 = __builtin_amdgcn_mfma_f32_16x16x32_f16(a1, b0, acc10, 0, 0, 0);
            acc11 = __builtin_amdgcn_mfma_f32_16x16x32_f16(a1, b1, acc11, 0, 0, 0);
        }
        int tsub  = t0 + sub * BM;
        int rbase = rowbase + ((lane >> 4) << 2);
#pragma unroll
        for (int reg = 0; reg < 4; ++reg) {
            int t = tsub + rbase + reg;
            if (t < TOUT) {
                float* o = &out[((size_t)b * TOUT + t) * NF];
                o[col0]      = sv * acc00[reg] + bc0;
                o[col0 + 16] = sv * acc01[reg] + bc1;
            }
            int t1 = t + 16;
            if (t1 < TOUT) {
                float* o = &out[((size_t)b * TOUT + t1) * NF];
                o[col0]      = sv * acc10[reg] + bc0;
                o[col0 + 16] = sv * acc11[reg] + bc1;
            }
        }
        if (sub < NSUB - 1) {
            __syncthreads();
            WRITEA();
            __syncthreads();
        }
    }
}

extern "C" void kernel_launch(void* const* d_in, const int* in_sizes, int n_in,
                              void* d_out, int out_size, void* d_ws, size_t ws_size,
                              hipStream_t stream) {
    const float* x     = (const float*)d_in[0];
    const float* Wconv = (const float*)d_in[1];
    const float* bconv = (const float*)d_in[2];
    const float* Wdef  = (const float*)d_in[3];
    float* out      = (float*)d_out;
    float* ws       = (float*)d_ws;
    float* partials = ws + 64;                                // byte 256, 256 KB

    dim3 grid((TOUT + NSUB * BM - 1) / (NSUB * BM), NB);      // 128 x 16

    chsum7_kernel<<<dim3(NCHB), dim3(256), 0, stream>>>(x, partials);
    if (ws_size >= 262400) {
        conv6_kernel<<<grid, dim3(256), 0, stream>>>(x, Wconv, bconv, Wdef, partials, out);
    } else {
        scalar2_kernel<<<dim3(1), dim3(256), 0, stream>>>(x, Wconv, bconv, Wdef, partials, ws);
        conv5_kernel<<<grid, dim3(256), 0, stream>>>(x, Wconv, bconv, ws, out);
    }
}

// Round 17
// 74.025 us; speedup vs baseline: 1.1017x; 1.1017x over previous
//
#include <hip/hip_runtime.h>
#include <hip/hip_fp16.h>

#define T    65536
#define TOUT 65532
#define NB   16
#define CH   32
#define NF   32
#define KS   5
#define BM   128
#define NSUB 4             // subtiles per conv block (512 rows)
#define NCHB 2048          // chsum grid; 2048*4096 float4 == NB*T*CH/4 exactly

typedef _Float16 f16x8 __attribute__((ext_vector_type(8)));
typedef _Float16 f16x4 __attribute__((ext_vector_type(4)));
typedef float    f32x4 __attribute__((ext_vector_type(4)));

// ws layout: ws[32] = scalar s; partials[2048][32] floats at byte 256 (256 KB).
// R15 champion restored (74.2 µs measured). Key structural facts learned:
//  - R6/R11: NO device-scope ordered atomics on gfx950 (release/acquire =>
//    per-XCD L2 writeback/invalidate storm). Kernel boundaries only.
//  - R15: no f16 intermediate — its 67 MB writeback costs more than it saves;
//    chsum's plain cached reads park x in L3 for conv.
//  - R16: redundant per-block s-prologue in conv regresses (block-head serial
//    reduction of partials ≫ launch+scalar2 savings). Keep 1-block scalar2.

__device__ __forceinline__ f16x4 cvt4(float4 v) {
    f16x4 h;
    h[0] = (_Float16)v.x; h[1] = (_Float16)v.y;
    h[2] = (_Float16)v.z; h[3] = (_Float16)v.w;
    return h;
}

// ---- K1: contiguous streaming chsum, plain cached loads (park x in L3) ----
__global__ __launch_bounds__(256) void chsum7_kernel(const float* __restrict__ x,
                                                     float* __restrict__ partials) {
    __shared__ float tot[CH];
    const int tid  = threadIdx.x;
    const int lane = tid & 63;
    if (tid < CH) tot[tid] = 0.f;
    __syncthreads();

    const float4* x4 = (const float4*)x;
    const size_t base = (size_t)blockIdx.x * 4096;   // contiguous 64 KB per block
    float s0 = 0.f, s1 = 0.f, s2 = 0.f, s3 = 0.f;
#pragma unroll 8
    for (int q = 0; q < 16; ++q) {
        float4 v = x4[base + (size_t)q * 256 + tid];  // cached: fills L3 for conv
        s0 += v.x; s1 += v.y; s2 += v.z; s3 += v.w;
    }
#pragma unroll
    for (int m = 8; m <= 32; m <<= 1) {    // lanes {l,l^8,l^16,l^32} share channel group
        s0 += __shfl_xor(s0, m, 64);
        s1 += __shfl_xor(s1, m, 64);
        s2 += __shfl_xor(s2, m, 64);
        s3 += __shfl_xor(s3, m, 64);
    }
    if (lane < 8) {
        const int cc = lane * 4;
        atomicAdd(&tot[cc + 0], s0);       // LDS atomics only
        atomicAdd(&tot[cc + 1], s1);
        atomicAdd(&tot[cc + 2], s2);
        atomicAdd(&tot[cc + 3], s3);
    }
    __syncthreads();
    if (tid < CH) partials[(size_t)blockIdx.x * CH + tid] = tot[tid];  // plain store
}

// ---- K2: one block reduces partials + edges -> scalar s ----
__global__ __launch_bounds__(256) void scalar2_kernel(const float* __restrict__ x,
                                                      const float* __restrict__ Wconv,
                                                      const float* __restrict__ bconv,
                                                      const float* __restrict__ Wdef,
                                                      const float* __restrict__ partials,
                                                      float* __restrict__ ws) {
    __shared__ float ltot[CH];
    __shared__ float hb[4][CH], tb[4][CH];
    __shared__ float partial[256];
    const int tid = threadIdx.x;
    if (tid < CH) ltot[tid] = 0.f;
    __syncthreads();
    {
        const float4* p4 = (const float4*)partials;   // 16384 float4, coalesced, hot
        float s0 = 0.f, s1 = 0.f, s2 = 0.f, s3 = 0.f;
#pragma unroll 8
        for (int i = 0; i < 64; ++i) {
            float4 v = p4[i * 256 + tid];
            s0 += v.x; s1 += v.y; s2 += v.z; s3 += v.w;
        }
        int cc = (tid & 7) * 4;
        atomicAdd(&ltot[cc + 0], s0);
        atomicAdd(&ltot[cc + 1], s1);
        atomicAdd(&ltot[cc + 2], s2);
        atomicAdd(&ltot[cc + 3], s3);
    }
    {
        int j = tid >> 5, c = tid & 31;               // j in 0..7
        int row = (j < 4) ? j : (T - 8 + j);
        float e = 0.f;
        for (int bb = 0; bb < NB; ++bb)
            e += x[((size_t)bb * T + row) * CH + c];
        if (j < 4) hb[j][c] = e; else tb[j - 4][c] = e;
    }
    __syncthreads();

    float term = 0.f;
    if (tid < KS * CH) {
        int k = tid >> 5, c = tid & 31;
        float wf = 0.f;
        const float* wp = &Wconv[(size_t)tid * NF];
        for (int f = 0; f < NF; ++f) wf += wp[f];
        float S = ltot[c];
        for (int jj = 0; jj < k; ++jj) S -= hb[jj][c];
        for (int jj = k; jj < 4; ++jj) S -= tb[jj][c];
        term = wf * S;
    }
    partial[tid] = term;
    __syncthreads();
    for (int off = 128; off > 0; off >>= 1) {
        if (tid < off) partial[tid] += partial[tid + off];
        __syncthreads();
    }
    if (tid == 0) {
        float sum_b = 0.f;
        for (int f = 0; f < NF; ++f) sum_b += bconv[f];
        float mean_off = partial[0] / (float)((size_t)NB * TOUT * NF) + sum_b / (float)NF;
        float s = 0.f;
        for (int k = 0; k < KS; ++k) {
            float pn = mean_off + (float)(k - 2);
            s += Wdef[k] * fmaxf(0.f, 1.f - fabsf(pn));
        }
        ws[CH] = s;
    }
}

// ---- K3: conv from f32 x (L3-hot); 4 subtiles/block, reg-prefetch, cvt in staging ----
__global__ __launch_bounds__(256) void conv5_kernel(const float* __restrict__ x,
                                                    const float* __restrict__ Wconv,
                                                    const float* __restrict__ bconv,
                                                    const float* __restrict__ ws,
                                                    float* __restrict__ out) {
    __shared__ _Float16 A[(BM + 4) * 40];
    __shared__ _Float16 Wt[KS * CH * 40];

    const int tid  = threadIdx.x;
    const int b    = blockIdx.y;
    const int t0   = blockIdx.x * (NSUB * BM);
    const int c0   = (tid & 7) * 4;
    const int srow = tid >> 3;               // 0..31

    const float* xb = x + (size_t)b * T * CH;

    // A-staging register buffers: rows srow+{0,32,64,96,128(if tid<32)}, f32
    float4 ra0, ra1, ra2, ra3, ra4;
    auto LOADA = [&](int sub) {
        const float* p = xb + (size_t)(t0 + sub * BM + srow) * CH + c0;
        ra0 = *(const float4*)(p);
        ra1 = *(const float4*)(p + 32 * CH);
        ra2 = *(const float4*)(p + 64 * CH);
        ra3 = *(const float4*)(p + 96 * CH);
        if (tid < 32) {
            int t = t0 + sub * BM + 128 + srow;
            ra4 = (t < T) ? *(const float4*)(xb + (size_t)t * CH + c0)
                          : make_float4(0.f, 0.f, 0.f, 0.f);
        }
    };
    auto WRITEA = [&]() {
        *(f16x4*)&A[(srow      ) * 40 + c0] = cvt4(ra0);
        *(f16x4*)&A[(srow + 32 ) * 40 + c0] = cvt4(ra1);
        *(f16x4*)&A[(srow + 64 ) * 40 + c0] = cvt4(ra2);
        *(f16x4*)&A[(srow + 96 ) * 40 + c0] = cvt4(ra3);
        if (tid < 32)
            *(f16x4*)&A[(128 + srow) * 40 + c0] = cvt4(ra4);
    };

    LOADA(0);
    // Wt[k][f][c] = Wconv[k][c][f] via coalesced float4 loads
    {
        const float4* w4 = (const float4*)Wconv;
#pragma unroll
        for (int j = 0; j < 5; ++j) {
            int i4 = tid + j * 256;
            float4 v = w4[i4];
            int fi = i4 * 4;
            int k = fi >> 10, c = (fi >> 5) & 31, f = fi & 31;
            _Float16* wrow = &Wt[(k * CH + f) * 40 + c];
            wrow[0 * 40] = (_Float16)v.x;
            wrow[1 * 40] = (_Float16)v.y;
            wrow[2 * 40] = (_Float16)v.z;
            wrow[3 * 40] = (_Float16)v.w;
        }
    }
    WRITEA();
    __syncthreads();

    const int lane = tid & 63;
    const int wave = tid >> 6;
    const int rowbase = wave * 32;
    const int lrow = lane & 15;
    const int kgrp = lane >> 4;
    const int col0 = lane & 15;
    const float sv  = ws[CH];
    const float bc0 = bconv[col0], bc1 = bconv[col0 + 16];

#pragma unroll
    for (int sub = 0; sub < NSUB; ++sub) {
        if (sub < NSUB - 1) LOADA(sub + 1);   // next tile's loads fly under MFMA+stores

        f32x4 acc00 = {}, acc01 = {}, acc10 = {}, acc11 = {};
#pragma unroll
        for (int kk = 0; kk < KS; ++kk) {
            f16x8 a0 = *(const f16x8*)&A[(rowbase + lrow + kk) * 40 + kgrp * 8];
            f16x8 a1 = *(const f16x8*)&A[(rowbase + 16 + lrow + kk) * 40 + kgrp * 8];
            f16x8 b0 = *(const f16x8*)&Wt[(kk * CH + lrow) * 40 + kgrp * 8];
            f16x8 b1 = *(const f16x8*)&Wt[(kk * CH + 16 + lrow) * 40 + kgrp * 8];
            acc00 = __builtin_amdgcn_mfma_f32_16x16x32_f16(a0, b0, acc00, 0, 0, 0);
            acc01 = __builtin_amdgcn_mfma_f32_16x16x32_f16(a0, b1, acc01, 0, 0, 0);
            acc10 = __builtin_amdgcn_mfma_f32_16x16x32_f16(a1, b0, acc10, 0, 0, 0);
            acc11 = __builtin_amdgcn_mfma_f32_16x16x32_f16(a1, b1, acc11, 0, 0, 0);
        }

        int tsub  = t0 + sub * BM;
        int rbase = rowbase + ((lane >> 4) << 2);
#pragma unroll
        for (int reg = 0; reg < 4; ++reg) {
            int t = tsub + rbase + reg;
            if (t < TOUT) {
                float* o = &out[((size_t)b * TOUT + t) * NF];
                o[col0]      = sv * acc00[reg] + bc0;
                o[col0 + 16] = sv * acc01[reg] + bc1;
            }
            int t1 = t + 16;
            if (t1 < TOUT) {
                float* o = &out[((size_t)b * TOUT + t1) * NF];
                o[col0]      = sv * acc10[reg] + bc0;
                o[col0 + 16] = sv * acc11[reg] + bc1;
            }
        }
        if (sub < NSUB - 1) {
            __syncthreads();               // all MFMA reads of A done
            WRITEA();                      // next tile into LDS
            __syncthreads();
        }
    }
}

extern "C" void kernel_launch(void* const* d_in, const int* in_sizes, int n_in,
                              void* d_out, int out_size, void* d_ws, size_t ws_size,
                              hipStream_t stream) {
    const float* x     = (const float*)d_in[0];
    const float* Wconv = (const float*)d_in[1];
    const float* bconv = (const float*)d_in[2];
    const float* Wdef  = (const float*)d_in[3];
    float* out      = (float*)d_out;
    float* ws       = (float*)d_ws;
    float* partials = ws + 64;                                // byte 256, 256 KB

    chsum7_kernel<<<dim3(NCHB), dim3(256), 0, stream>>>(x, partials);
    scalar2_kernel<<<dim3(1), dim3(256), 0, stream>>>(x, Wconv, bconv, Wdef, partials, ws);
    dim3 grid((TOUT + NSUB * BM - 1) / (NSUB * BM), NB);      // 128 x 16
    conv5_kernel<<<grid, dim3(256), 0, stream>>>(x, Wconv, bconv, ws, out);
}